// Round 2
// baseline (9170.431 us; speedup 1.0000x reference)
//
#include <hip/hip_runtime.h>
#include <cstdint>

#define NS 2048      // states S
#define NE 65536     // arcs E
#define ND 2048      // pdfs D
#define NB 32        // batch
#define NT 500       // frames
#define NGROUPS 32   // 64-state groups
#define ELLCAP (3*NE)
#define LEAKYF 0.1f
#define NBG 16       // batch groups (2 batches each)
#define NSP 16       // state partitions (128 states each)
#define NWG 256

// ws byte offsets
#define WS_COUNTS   0
#define WS_CURSOR   8192
#define WS_WIDTHS   16384
#define WS_GBASE    16512
#define WS_BARSUB   17408
#define WS_BARROOT  18432
#define WS_ALBUF    20480
#define WS_ARC      544768   // 20480 + 2*16*2048*2*4

__global__ void k_init(const float* __restrict__ log_init, float* albuf,
                       uint32_t* counts, uint32_t* cursor, uint2* arc,
                       uint32_t* barsub, uint32_t* barroot, float* out) {
    int tid = blockIdx.x * blockDim.x + threadIdx.x;
    int n = blockDim.x * gridDim.x;
    for (int i = tid; i < NS; i += n) { counts[i] = 0u; cursor[i] = 0u; }
    for (int i = tid; i < ELLCAP; i += n) arc[i] = make_uint2(0u, 0u);
    for (int i = tid; i < NBG * NS; i += n) {
        int s = i & (NS - 1);
        float a = __expf(log_init[s]);
        reinterpret_cast<float2*>(albuf)[i] = make_float2(a, a);  // buf0: [bg][s][2b]
    }
    for (int i = tid; i < 256; i += n) barsub[i] = 0u;
    if (tid == 0) { *barroot = 0u; out[0] = 0.0f; }
}

__global__ void k_count(const int* __restrict__ to_state, uint32_t* counts) {
    int e = blockIdx.x * blockDim.x + threadIdx.x;
    if (e < NE) atomicAdd(&counts[to_state[e]], 1u);
}

__global__ void k_widths(const uint32_t* __restrict__ counts, uint32_t* widths, uint32_t* gbase) {
    int g = threadIdx.x;
    if (g < NGROUPS) {
        uint32_t w = 0u;
        for (int i = 0; i < 64; ++i) w = max(w, counts[g*64 + i]);
        widths[g] = w;
    }
    __syncthreads();
    if (threadIdx.x == 0) {
        uint32_t acc = 0u;
        for (int g2 = 0; g2 < NGROUPS; ++g2) { gbase[g2] = acc; acc += widths[g2] * 64u; }
        gbase[NGROUPS] = acc;
    }
}

__global__ void k_scatter(const int* __restrict__ from_state, const int* __restrict__ to_state,
                          const int* __restrict__ pdf_ids, const float* __restrict__ log_w,
                          const uint32_t* __restrict__ gbase, uint32_t* cursor, uint2* arc) {
    int e = blockIdx.x * blockDim.x + threadIdx.x;
    if (e >= NE) return;
    int s = to_state[e];
    int g = s >> 6;
    uint32_t slot = atomicAdd(&cursor[s], 1u);
    uint32_t pos = gbase[g] + slot * 64u + (uint32_t)(s & 63);
    uint32_t meta = (uint32_t)from_state[e] | ((uint32_t)pdf_ids[e] << 16);
    float w = __expf(log_w[e]);
    arc[pos] = make_uint2(meta, __float_as_uint(w));
}

// Persistent grid: 256 WGs = 16 batch-groups x 16 state-partitions.
// Alpha double-buffered in global; one hierarchical device barrier per step.
__global__ __launch_bounds__(1024, 1) void k_fwd(
    const float* __restrict__ x, const float* __restrict__ log_init,
    const float* __restrict__ log_final,
    const uint2* __restrict__ arc, const uint32_t* __restrict__ widths,
    const uint32_t* __restrict__ gbase,
    float* __restrict__ albuf, uint32_t* barsub, uint32_t* barroot, float* out)
{
    __shared__ __align__(16) float e2[NS*2];     // [s][2b] 16KB
    __shared__ __align__(16) float Xs[ND*2];     // [d][2b] 16KB
    __shared__ __align__(16) float initL[NS];    // 8KB
    __shared__ __align__(16) float pt[16*64*2];  // [wid][lane][2b] 8KB
    __shared__ __align__(16) float red[16*2];

    const int tid  = threadIdx.x;
    const int wgid = blockIdx.x;
    const int bg   = wgid >> 4;
    const int sp   = wgid & 15;
    const int lane = tid & 63;
    const int wid  = tid >> 6;
    const int gsel = wid >> 3;   // which of my 2 groups
    const int wsl  = wid & 7;    // slot-slice within group
    const int g    = sp*2 + gsel;

    for (int i = tid; i < NS; i += 1024) initL[i] = __expf(log_init[i]);

    const float* x0 = x + (size_t)(2*bg)     * NT * ND;
    const float* x1 = x + (size_t)(2*bg + 1) * NT * ND;

    {   // Xs for t=0
        float2 a0 = *reinterpret_cast<const float2*>(x0 + tid*2);
        float2 a1 = *reinterpret_cast<const float2*>(x1 + tid*2);
        Xs[tid*4+0] = __expf(a0.x);
        Xs[tid*4+1] = __expf(a1.x);
        Xs[tid*4+2] = __expf(a0.y);
        Xs[tid*4+3] = __expf(a1.y);
    }

    const uint32_t gb = gbase[g];
    const int wd = (int)widths[g];
    const uint2* ap = arc + gb + lane;   // slot i at ap[i*64]

    float C0 = 0.f, C1 = 0.f;

    for (int t = 0; t < NT; ++t) {
        const int cb = t & 1;
        const int nb = cb ^ 1;

        // stage cur alpha (full 2048 states x 2 batches) + total mass
        float4 v = *reinterpret_cast<const float4*>(
            albuf + (size_t)(cb*NBG + bg)*NS*2 + tid*4);
        float s0 = v.x + v.z, s1 = v.y + v.w;
        #pragma unroll
        for (int off = 32; off > 0; off >>= 1) {
            s0 += __shfl_down(s0, off, 64);
            s1 += __shfl_down(s1, off, 64);
        }
        if (lane == 0) { red[wid*2] = s0; red[wid*2+1] = s1; }
        __syncthreads();                                  // (A)
        float T0 = 0.f, T1 = 0.f;
        #pragma unroll
        for (int j = 0; j < 8; ++j) {
            float4 q = *reinterpret_cast<const float4*>(&red[j*4]);
            T0 += q.x + q.z; T1 += q.y + q.w;
        }
        float i0 = 1.0f / T0, i1 = 1.0f / T1;
        C0 += __logf(T0); C1 += __logf(T1);

        // issue x prefetch for t+1 (hidden under arc pass)
        float2 b0, b1;
        const bool pf = (t + 1 < NT);
        if (pf) {
            b0 = *reinterpret_cast<const float2*>(x0 + (size_t)(t+1)*ND + tid*2);
            b1 = *reinterpret_cast<const float2*>(x1 + (size_t)(t+1)*ND + tid*2);
        }

        // leaky + normalize into LDS:  e2 = a/T + LEAKY*init
        {
            int s2 = tid*2;
            float l0 = LEAKYF * initL[s2], l1 = LEAKYF * initL[s2+1];
            e2[tid*4+0] = v.x*i0 + l0;
            e2[tid*4+1] = v.y*i1 + l0;
            e2[tid*4+2] = v.z*i0 + l1;
            e2[tid*4+3] = v.w*i1 + l1;
        }
        __syncthreads();                                  // (B) e2+Xs ready

        // arc pass: my group's ELL slots wsl, wsl+8, ... ; lane = dest state in group
        float p0 = 0.f, p1 = 0.f;
        for (int i = wsl; i < wd; i += 8) {
            uint2 A = ap[(size_t)i * 64];
            float w = __uint_as_float(A.y);
            int src = A.x & 0xFFFF, pdf = A.x >> 16;
            float2 ev = *reinterpret_cast<const float2*>(&e2[src*2]);
            float2 xv = *reinterpret_cast<const float2*>(&Xs[pdf*2]);
            p0 += ev.x * w * xv.x;
            p1 += ev.y * w * xv.y;
        }
        *reinterpret_cast<float2*>(&pt[(wid*64 + lane)*2]) = make_float2(p0, p1);
        __syncthreads();                                  // (C)

        // reduce 8 wave-partials per state, write my 128 states to next buffer
        if (tid < 128) {
            int g2 = tid >> 6, ln = tid & 63;
            float r0 = 0.f, r1 = 0.f;
            #pragma unroll
            for (int w2 = 0; w2 < 8; ++w2) {
                float2 q = *reinterpret_cast<const float2*>(&pt[((g2*8 + w2)*64 + ln)*2]);
                r0 += q.x; r1 += q.y;
            }
            int st = (sp*2 + g2)*64 + ln;
            *reinterpret_cast<float2*>(albuf + (size_t)(nb*NBG + bg)*NS*2 + st*2)
                = make_float2(r0, r1);
        }
        if (pf) {   // finish Xs(t+1) while stores drain
            Xs[tid*4+0] = __expf(b0.x);
            Xs[tid*4+1] = __expf(b1.x);
            Xs[tid*4+2] = __expf(b0.y);
            Xs[tid*4+3] = __expf(b1.y);
        }
        __syncthreads();                                  // (D) all stores issued

        // grid barrier: hierarchical, monotonic (no reset)
        if (tid == 0) {
            __threadfence();  // release my WG's alpha writes
            uint32_t old = __hip_atomic_fetch_add(&barsub[sp*16], 1u,
                               __ATOMIC_ACQ_REL, __HIP_MEMORY_SCOPE_AGENT);
            if ((old & 15u) == 15u)
                __hip_atomic_fetch_add(barroot, 1u,
                    __ATOMIC_ACQ_REL, __HIP_MEMORY_SCOPE_AGENT);
            const uint32_t target = (uint32_t)(t + 1) * 16u;
            while (__hip_atomic_load(barroot, __ATOMIC_RELAXED,
                                     __HIP_MEMORY_SCOPE_AGENT) < target)
                __builtin_amdgcn_s_sleep(1);
            __threadfence();  // acquire everyone's alpha writes
        }
        __syncthreads();                                  // (E)
    }

    // epilogue: sp==0 WG of each batch-group computes objf for its 2 batches
    if (sp == 0) {
        const int fb = NT & 1;
        float4 v = *reinterpret_cast<const float4*>(
            albuf + (size_t)(fb*NBG + bg)*NS*2 + tid*4);
        int s2 = tid*2;
        float ef0 = __expf(log_final[s2]), ef1 = __expf(log_final[s2+1]);
        float s0 = v.x*ef0 + v.z*ef1;
        float s1 = v.y*ef0 + v.w*ef1;
        #pragma unroll
        for (int off = 32; off > 0; off >>= 1) {
            s0 += __shfl_down(s0, off, 64);
            s1 += __shfl_down(s1, off, 64);
        }
        if (lane == 0) { red[wid*2] = s0; red[wid*2+1] = s1; }
        __syncthreads();
        if (tid == 0) {
            float t0 = 0.f, t1 = 0.f;
            #pragma unroll
            for (int j = 0; j < 8; ++j) {
                float4 q = *reinterpret_cast<const float4*>(&red[j*4]);
                t0 += q.x + q.z; t1 += q.y + q.w;
            }
            atomicAdd(out, -(__logf(t0) + C0) - (__logf(t1) + C1));
        }
    }
}

extern "C" void kernel_launch(void* const* d_in, const int* in_sizes, int n_in,
                              void* d_out, int out_size, void* d_ws, size_t ws_size,
                              hipStream_t stream) {
    const float* x         = (const float*)d_in[0];
    const float* log_w     = (const float*)d_in[1];
    const float* log_init  = (const float*)d_in[2];
    const float* log_final = (const float*)d_in[3];
    const int*   from_st   = (const int*)d_in[4];
    const int*   to_st     = (const int*)d_in[5];
    const int*   pdf_ids   = (const int*)d_in[6];
    float* out = (float*)d_out;

    uint8_t* ws = (uint8_t*)d_ws;
    uint32_t* counts  = (uint32_t*)(ws + WS_COUNTS);
    uint32_t* cursor  = (uint32_t*)(ws + WS_CURSOR);
    uint32_t* widths  = (uint32_t*)(ws + WS_WIDTHS);
    uint32_t* gbase   = (uint32_t*)(ws + WS_GBASE);
    uint32_t* barsub  = (uint32_t*)(ws + WS_BARSUB);
    uint32_t* barroot = (uint32_t*)(ws + WS_BARROOT);
    float*    albuf   = (float*)(ws + WS_ALBUF);
    uint2*    arc     = (uint2*)(ws + WS_ARC);

    k_init   <<<512, 256, 0, stream>>>(log_init, albuf, counts, cursor, arc, barsub, barroot, out);
    k_count  <<<NE/256, 256, 0, stream>>>(to_st, counts);
    k_widths <<<1, 64, 0, stream>>>(counts, widths, gbase);
    k_scatter<<<NE/256, 256, 0, stream>>>(from_st, to_st, pdf_ids, log_w, gbase, cursor, arc);
    k_fwd    <<<NWG, 1024, 0, stream>>>(x, log_init, log_final, arc, widths, gbase,
                                        albuf, barsub, barroot, out);
}

// Round 3
// 2168.005 us; speedup vs baseline: 4.2299x; 4.2299x over previous
//
#include <hip/hip_runtime.h>
#include <cstdint>

#define NS 2048      // states S
#define NE 65536     // arcs E
#define ND 2048      // pdfs D
#define NB 32        // batch
#define NT 500       // frames
#define NGROUPS 32   // 64-state groups
#define ELLCAP (3*NE)
#define LEAKYF 0.1f
#define NSP 8        // state partitions (256 states each)

// ws byte offsets
#define WS_COUNTS   0
#define WS_CURSOR   8192
#define WS_WIDTHS   16384
#define WS_GBASE    16512
#define WS_BARCNT   17408     // 32 batches x 128B line
#define WS_ALBUF    21504     // 2*32*2048*4 = 524288
#define WS_ARC      545792    // ELLCAP*8 = 1572864

// ---- per-op device-coherent (L3) access, NO cache-wide fences ----
__device__ __forceinline__ void st_pair(float* p, float a, float b) {
    union { float f[2]; unsigned long long u; } q; q.f[0] = a; q.f[1] = b;
    __hip_atomic_store(reinterpret_cast<unsigned long long*>(p), q.u,
                       __ATOMIC_RELAXED, __HIP_MEMORY_SCOPE_AGENT);
}
__device__ __forceinline__ float2 ld_pair(const float* p) {
    unsigned long long u = __hip_atomic_load(
        reinterpret_cast<const unsigned long long*>(p),
        __ATOMIC_RELAXED, __HIP_MEMORY_SCOPE_AGENT);
    union { unsigned long long u; float f[2]; } q; q.u = u;
    return make_float2(q.f[0], q.f[1]);
}

__global__ void k_init(const float* __restrict__ log_init, float* albuf,
                       uint32_t* counts, uint32_t* cursor, uint2* arc,
                       uint32_t* barcnt, float* out) {
    int tid = blockIdx.x * blockDim.x + threadIdx.x;
    int n = blockDim.x * gridDim.x;
    for (int i = tid; i < NS; i += n) { counts[i] = 0u; cursor[i] = 0u; }
    for (int i = tid; i < ELLCAP; i += n) arc[i] = make_uint2(0u, 0u);
    for (int i = tid; i < NB * NS; i += n)
        albuf[i] = __expf(log_init[i & (NS - 1)]);   // buf0: [b][s]
    for (int i = tid; i < 32 * 32; i += n) barcnt[i] = 0u;
    if (tid == 0) out[0] = 0.0f;
}

__global__ void k_count(const int* __restrict__ to_state, uint32_t* counts) {
    int e = blockIdx.x * blockDim.x + threadIdx.x;
    if (e < NE) atomicAdd(&counts[to_state[e]], 1u);
}

__global__ void k_widths(const uint32_t* __restrict__ counts, uint32_t* widths, uint32_t* gbase) {
    int g = threadIdx.x;
    if (g < NGROUPS) {
        uint32_t w = 0u;
        for (int i = 0; i < 64; ++i) w = max(w, counts[g*64 + i]);
        widths[g] = w;
    }
    __syncthreads();
    if (threadIdx.x == 0) {
        uint32_t acc = 0u;
        for (int g2 = 0; g2 < NGROUPS; ++g2) { gbase[g2] = acc; acc += widths[g2] * 64u; }
        gbase[NGROUPS] = acc;
    }
}

__global__ void k_scatter(const int* __restrict__ from_state, const int* __restrict__ to_state,
                          const int* __restrict__ pdf_ids, const float* __restrict__ log_w,
                          const uint32_t* __restrict__ gbase, uint32_t* cursor, uint2* arc) {
    int e = blockIdx.x * blockDim.x + threadIdx.x;
    if (e >= NE) return;
    int s = to_state[e];
    int g = s >> 6;
    uint32_t slot = atomicAdd(&cursor[s], 1u);
    uint32_t pos = gbase[g] + slot * 64u + (uint32_t)(s & 63);
    uint32_t meta = (uint32_t)from_state[e] | ((uint32_t)pdf_ids[e] << 16);
    float w = __expf(log_w[e]);
    arc[pos] = make_uint2(meta, __float_as_uint(w));
}

// 256 persistent WGs: bid = sp*32 + b  (batch b, state-partition sp).
// A batch's 8 WGs share bid%8 -> same XCD (L2 locality for x row).
// Alpha ping-pong in global via per-op coherent atomics; per-batch counter barrier.
__global__ __launch_bounds__(1024, 1) void k_fwd(
    const float* __restrict__ x, const float* __restrict__ log_init,
    const float* __restrict__ log_final,
    const uint2* __restrict__ arc, const uint32_t* __restrict__ widths,
    const uint32_t* __restrict__ gbase,
    float* __restrict__ albuf, uint32_t* __restrict__ barcnt, float* out)
{
    __shared__ __align__(16) float e2[NS];     // 8 KB
    __shared__ __align__(16) float Xs[ND];     // 8 KB
    __shared__ __align__(16) float pt[16*64];  // 4 KB
    __shared__ float red[16];

    const int tid  = threadIdx.x;
    const int b    = blockIdx.x & 31;
    const int sp   = blockIdx.x >> 5;
    const int lane = tid & 63;
    const int wid  = tid >> 6;
    const int g    = sp * 4 + (wid >> 2);   // my 64-state group
    const int wsl  = wid & 3;               // ELL slot slice (4 waves/group)

    const float init0 = LEAKYF * __expf(log_init[2*tid]);
    const float init1 = LEAKYF * __expf(log_init[2*tid + 1]);
    const float* xrow = x + (size_t)b * NT * ND;

    {   // Xs(0)
        float2 xv = *reinterpret_cast<const float2*>(xrow + 2*tid);
        Xs[2*tid]     = __expf(xv.x);
        Xs[2*tid + 1] = __expf(xv.y);
    }

    const uint32_t gb = gbase[g];
    const int wd = (int)widths[g];
    const uint2* ap = arc + gb + lane;            // slot i at ap[i*64]
    uint32_t* mycnt = barcnt + b * 32;            // one 128B line per batch

    float C = 0.0f;
    __syncthreads();

    for (int t = 0; t < NT; ++t) {
        const int cb = t & 1, nbuf_i = cb ^ 1;
        const float* cbuf = albuf + (size_t)(cb * NB + b) * NS;
        float*       nbuf = albuf + (size_t)(nbuf_i * NB + b) * NS;

        // stage full alpha (device-coherent pair load)
        float2 v = ld_pair(cbuf + 2*tid);

        // prefetch x(t+1) into regs (hidden under reduction + arc pass)
        float2 b0;
        const bool pf = (t + 1 < NT);
        if (pf) b0 = *reinterpret_cast<const float2*>(xrow + (size_t)(t+1)*ND + 2*tid);

        // total mass T (identical order in all 8 WGs -> bitwise-identical)
        float s0 = v.x + v.y;
        #pragma unroll
        for (int off = 32; off > 0; off >>= 1) s0 += __shfl_down(s0, off, 64);
        if (lane == 0) red[wid] = s0;
        __syncthreads();                               // (A)
        float T = 0.f;
        #pragma unroll
        for (int j = 0; j < 16; ++j) T += red[j];
        float invT = 1.0f / T;
        C += __logf(T);

        // leaky + normalize into LDS
        e2[2*tid]     = v.x * invT + init0;
        e2[2*tid + 1] = v.y * invT + init1;
        __syncthreads();                               // (B) e2 (+Xs) ready

        // arc pass over my group's ELL slots (lane = dest state in group)
        float acc = 0.f;
        for (int i = wsl; i < wd; i += 4) {
            uint2 A = ap[(size_t)i * 64];
            acc += e2[A.x & 0xFFFFu] * __uint_as_float(A.y) * Xs[A.x >> 16];
        }
        pt[wid * 64 + lane] = acc;
        __syncthreads();                               // (C)

        // reduce 4 wave-partials per state; coherent pair-store my 256 states
        if (tid < 128) {
            int s2 = 2 * tid;                 // partition-local state (even)
            int g2 = s2 >> 6, l0 = s2 & 63;
            float r0 = pt[(g2*4+0)*64 + l0] + pt[(g2*4+1)*64 + l0]
                     + pt[(g2*4+2)*64 + l0] + pt[(g2*4+3)*64 + l0];
            float r1 = pt[(g2*4+0)*64 + l0+1] + pt[(g2*4+1)*64 + l0+1]
                     + pt[(g2*4+2)*64 + l0+1] + pt[(g2*4+3)*64 + l0+1];
            st_pair(nbuf + sp * 256 + s2, r0, r1);
        }
        if (pf) {   // finish Xs(t+1)
            Xs[2*tid]     = __expf(b0.x);
            Xs[2*tid + 1] = __expf(b0.y);
        }
        __syncthreads();   // (D) drains vmcnt per wave -> stores at L3

        // per-batch monotonic counter barrier (8 arrivals/step, no fences)
        if (tid == 0) {
            __hip_atomic_fetch_add(mycnt, 1u, __ATOMIC_RELAXED,
                                   __HIP_MEMORY_SCOPE_AGENT);
            const uint32_t tgt = (uint32_t)NSP * (uint32_t)(t + 1);
            while (__hip_atomic_load(mycnt, __ATOMIC_RELAXED,
                                     __HIP_MEMORY_SCOPE_AGENT) < tgt)
                __builtin_amdgcn_s_sleep(1);
        }
        __syncthreads();                               // (E)
    }

    // epilogue: sp==0 WG of each batch
    if (sp == 0) {
        const int fb = NT & 1;   // NT even -> 0
        const float* fbuf = albuf + (size_t)(fb * NB + b) * NS;
        float2 v = ld_pair(fbuf + 2*tid);
        float s0 = v.x * __expf(log_final[2*tid])
                 + v.y * __expf(log_final[2*tid + 1]);
        #pragma unroll
        for (int off = 32; off > 0; off >>= 1) s0 += __shfl_down(s0, off, 64);
        if (lane == 0) red[wid] = s0;
        __syncthreads();
        if (tid == 0) {
            float tot = 0.f;
            #pragma unroll
            for (int j = 0; j < 16; ++j) tot += red[j];
            atomicAdd(out, -(__logf(tot) + C));
        }
    }
}

extern "C" void kernel_launch(void* const* d_in, const int* in_sizes, int n_in,
                              void* d_out, int out_size, void* d_ws, size_t ws_size,
                              hipStream_t stream) {
    const float* x         = (const float*)d_in[0];
    const float* log_w     = (const float*)d_in[1];
    const float* log_init  = (const float*)d_in[2];
    const float* log_final = (const float*)d_in[3];
    const int*   from_st   = (const int*)d_in[4];
    const int*   to_st     = (const int*)d_in[5];
    const int*   pdf_ids   = (const int*)d_in[6];
    float* out = (float*)d_out;

    uint8_t* ws = (uint8_t*)d_ws;
    uint32_t* counts  = (uint32_t*)(ws + WS_COUNTS);
    uint32_t* cursor  = (uint32_t*)(ws + WS_CURSOR);
    uint32_t* widths  = (uint32_t*)(ws + WS_WIDTHS);
    uint32_t* gbase   = (uint32_t*)(ws + WS_GBASE);
    uint32_t* barcnt  = (uint32_t*)(ws + WS_BARCNT);
    float*    albuf   = (float*)(ws + WS_ALBUF);
    uint2*    arc     = (uint2*)(ws + WS_ARC);

    k_init   <<<512, 256, 0, stream>>>(log_init, albuf, counts, cursor, arc, barcnt, out);
    k_count  <<<NE/256, 256, 0, stream>>>(to_st, counts);
    k_widths <<<1, 64, 0, stream>>>(counts, widths, gbase);
    k_scatter<<<NE/256, 256, 0, stream>>>(from_st, to_st, pdf_ids, log_w, gbase, cursor, arc);
    k_fwd    <<<NSP*NB, 1024, 0, stream>>>(x, log_init, log_final, arc, widths, gbase,
                                           albuf, barcnt, out);
}